// Round 1
// 1088.370 us; speedup vs baseline: 1.0048x; 1.0048x over previous
//
#include <hip/hip_runtime.h>
#include <math.h>

#pragma clang fp contract(off)   // no implicit fusion; FMA only where ref has it

// Problem constants (fixed by the reference)
#define BB   8
#define NN   16384
#define FF   32
#define SS   2048
#define KK   32
#define OUTC 128

// force a value into uniform (SGPR) representation
__device__ __forceinline__ float uni(float v) {
    return __uint_as_float(__builtin_amdgcn_readfirstlane(__float_as_uint(v)));
}

// prefix popcount of 64-bit ballot below this lane (2 VALU ops)
__device__ __forceinline__ int mbcnt64(unsigned long long m) {
    return __builtin_amdgcn_mbcnt_hi((unsigned)(m >> 32),
           __builtin_amdgcn_mbcnt_lo((unsigned)m, 0));
}

// ---------------------------------------------------------------------------
// Reference-bit-exact fp32 helpers (validated R0-R7):
// x_sq / s_sq: numpy pairwise_sum scalar 8-accumulator block (n=32, no FMA)
__device__ __forceinline__ float np_sumsq32(const float* a) {
    float r[8];
#pragma unroll
    for (int j = 0; j < 8; j++) r[j] = a[j] * a[j];
#pragma unroll
    for (int t = 1; t < 4; t++) {
#pragma unroll
        for (int j = 0; j < 8; j++) {
            float e = a[8 * t + j] * a[8 * t + j];
            r[j] = r[j] + e;
        }
    }
    return ((r[0] + r[1]) + (r[2] + r[3])) + ((r[4] + r[5]) + (r[6] + r[7]));
}

// ---------------------------------------------------------------------------
// K1a: x_sq[b,n] = ref-order sum_f x^2
__global__ __launch_bounds__(256) void xsq_kernel(const float* __restrict__ x,
                                                  float* __restrict__ xsq) {
    int gid = blockIdx.x * 256 + threadIdx.x;      // < B*N
    const float4* r = (const float4*)(x + (size_t)gid * FF);
    float a[32];
#pragma unroll
    for (int j = 0; j < 8; j++) {
        float4 v = r[j];
        a[4 * j] = v.x; a[4 * j + 1] = v.y; a[4 * j + 2] = v.z; a[4 * j + 3] = v.w;
    }
    xsq[gid] = np_sumsq32(a);
}

// ---------------------------------------------------------------------------
// K1b: gather sampled features (row-major [B,S,F]) + ref-order s_sq
__global__ __launch_bounds__(256) void gather_kernel(const float* __restrict__ x,
                                                     const int* __restrict__ sidx,
                                                     float* __restrict__ sampled,
                                                     float* __restrict__ ssq) {
    int gid = blockIdx.x * 256 + threadIdx.x;      // < B*S
    int b = gid >> 11;
    int idx = sidx[gid];
    const float4* r = (const float4*)(x + ((size_t)b * NN + idx) * FF);
    float4* wo = (float4*)(sampled + (size_t)gid * FF);
    float a[32];
#pragma unroll
    for (int j = 0; j < 8; j++) {
        float4 v = r[j];
        a[4 * j] = v.x; a[4 * j + 1] = v.y; a[4 * j + 2] = v.z; a[4 * j + 3] = v.w;
        wo[j] = v;
    }
    ssq[gid] = np_sumsq32(a);
}

// ---------------------------------------------------------------------------
// K1c: sampled [B,S,F] -> output sampled_batch [B,F,S] (transpose via LDS)
__global__ __launch_bounds__(256) void transpose_kernel(const float* __restrict__ sampled,
                                                        float* __restrict__ out_samp) {
    __shared__ float tile[32][65];
    int b = blockIdx.x >> 5, sg = blockIdx.x & 31;
    int s0 = sg * 64;
    int tid = threadIdx.x;
    int f = tid & 31, si = tid >> 5;               // si in 0..7
#pragma unroll
    for (int r = 0; r < 8; r++) {
        int s = r * 8 + si;
        tile[f][s] = sampled[((size_t)b * SS + s0 + s) * FF + f];
    }
    __syncthreads();
#pragma unroll
    for (int r = 0; r < 8; r++) {
        int flat = r * 256 + tid;
        int fo = flat >> 6, sw = flat & 63;
        out_samp[((size_t)b * FF + fo) * SS + s0 + sw] = tile[fo][sw];
    }
}

// ---------------------------------------------------------------------------
// K2: per-point MLP, h2[b,n,:] = W2 @ relu(W1 @ x + b1) + b2  (fp32, VALU)
__global__ __launch_bounds__(256) void mlp_kernel(const float* __restrict__ x,
                                                  const float* __restrict__ W1,
                                                  const float* __restrict__ b1,
                                                  const float* __restrict__ W2,
                                                  const float* __restrict__ b2,
                                                  float* __restrict__ h2) {
    __shared__ float xs[64][36];          // padded
    __shared__ float hs[8512];            // h1t [128][65] then reused as h2s [64][133]
    int tid = threadIdx.x, lane = tid & 63;
    int wu = __builtin_amdgcn_readfirstlane(tid >> 6);
    size_t p0 = (size_t)blockIdx.x * 64;

    for (int i = tid; i < 64 * 8; i += 256) {
        int row = i >> 3, seg = i & 7;
        *(float4*)&xs[row][seg * 4] = *(const float4*)(x + (p0 + row) * FF + seg * 4);
    }
    __syncthreads();

    float xr[32];
    {
        const float4* r = (const float4*)&xs[lane][0];
#pragma unroll
        for (int j = 0; j < 8; j++) {
            float4 v = r[j];
            xr[4 * j] = v.x; xr[4 * j + 1] = v.y; xr[4 * j + 2] = v.z; xr[4 * j + 3] = v.w;
        }
    }
#pragma unroll 4
    for (int i = 0; i < 32; i++) {
        int o = wu * 32 + i;
        const float4* wr = (const float4*)(W1 + o * FF);
        float a = b1[o];
#pragma unroll
        for (int j = 0; j < 8; j++) {
            float4 v = wr[j];
            a = fmaf(v.x, xr[4 * j], a);     a = fmaf(v.y, xr[4 * j + 1], a);
            a = fmaf(v.z, xr[4 * j + 2], a); a = fmaf(v.w, xr[4 * j + 3], a);
        }
        hs[o * 65 + lane] = fmaxf(a, 0.f);
    }
    __syncthreads();
    float acc[32];
#pragma unroll
    for (int i = 0; i < 32; i++) acc[i] = b2[wu * 32 + i];
    for (int k4 = 0; k4 < 32; k4++) {
        float h0 = hs[(4 * k4 + 0) * 65 + lane];
        float h1v = hs[(4 * k4 + 1) * 65 + lane];
        float h2v = hs[(4 * k4 + 2) * 65 + lane];
        float h3v = hs[(4 * k4 + 3) * 65 + lane];
#pragma unroll
        for (int i = 0; i < 32; i++) {
            const float4 v = *(const float4*)(W2 + (wu * 32 + i) * OUTC + 4 * k4);
            acc[i] = fmaf(v.x, h0, acc[i]);  acc[i] = fmaf(v.y, h1v, acc[i]);
            acc[i] = fmaf(v.z, h2v, acc[i]); acc[i] = fmaf(v.w, h3v, acc[i]);
        }
    }
    __syncthreads();
#pragma unroll 4
    for (int i = 0; i < 32; i++) hs[lane * 133 + wu * 32 + i] = acc[i];
    __syncthreads();
    for (int j = 0; j < 32; j++) {
        int flat = j * 256 + tid;
        int p = flat >> 7, o = flat & 127;
        h2[(p0 + p) * OUTC + o] = hs[p * 133 + o];
    }
}

// ---------------------------------------------------------------------------
// K3 v5: SGPR queries (R9) + SINGLE-buffer LDS with register prefetch and
// TWO barriers per tile, sized so ALL 2048 blocks are co-resident:
// LDS/block = 9216 (xs) + 8192 (buf) = 17408 B -> 8 blocks/CU = 32 waves/CU
// (100% occupancy cap), grid 2048 = 256 CU x 8 exactly: one round, no tail.
// Previous double-buffer version was 26624 B -> 4 blocks/CU = 48% occupancy,
// VALUBusy 49.5%; barrier skew is now hidden by 7 other resident blocks.
__device__ __forceinline__ bool lessp(float da, int ia, float db, int ib) {
    return da < db || (da == db && ia < ib);
}
__device__ __forceinline__ void cswap(float& d, int& i, int j, bool dirAsc, int lane) {
    float od = __shfl_xor(d, j);
    int   oi = __shfl_xor(i, j);
    bool lower = (lane & j) == 0;
    bool oLess = lessp(od, oi, d, i);
    if (oLess == (lower == dirAsc)) { d = od; i = oi; }
}
__device__ __forceinline__ void sort64(float& d, int& i, bool asc, int lane) {
#pragma unroll
    for (int k = 2; k <= 64; k <<= 1) {
        bool ba = (((lane & k) == 0) == asc);
#pragma unroll
        for (int j = k >> 1; j > 0; j >>= 1) cswap(d, i, j, ba, lane);
    }
}
// sort m valid slots, keep lowest-64 lex-sorted in [0,64); return 32nd-smallest
__device__ __forceinline__ float wave_compact2(float* bd, int* bi, int m, int lane) {
    float d0 = (lane < m) ? bd[lane] : INFINITY;
    int   i0 = (lane < m) ? bi[lane] : 0x7fffffff;
    float d1 = (lane + 64 < m) ? bd[lane + 64] : INFINITY;
    int   i1 = (lane + 64 < m) ? bi[lane + 64] : 0x7fffffff;
    sort64(d0, i0, true, lane);
    sort64(d1, i1, false, lane);
    bool t = lessp(d1, i1, d0, i0);
    float ld = t ? d1 : d0;
    int   li = t ? i1 : i0;
#pragma unroll
    for (int j = 32; j > 0; j >>= 1) cswap(ld, li, j, true, lane);
    bd[lane] = ld; bi[lane] = li;
    return uni(__shfl(ld, 31));            // uniform across wave
}

__global__ __launch_bounds__(256, 8) void topk_kernel(const float* __restrict__ x,
                                                      const float* __restrict__ x_sq,
                                                      const float* __restrict__ sampled,
                                                      const float* __restrict__ s_sq,
                                                      int* __restrict__ nbr) {
    int b = blockIdx.x & 7;                 // XCD-by-batch swizzle
    int qg = blockIdx.x >> 3;               // 0..255
    int tid = threadIdx.x, lane = tid & 63;
    int w = __builtin_amdgcn_readfirstlane(tid >> 6);
    __shared__ float xs[64][36];            // single buffer, padded rows (9216 B)
    __shared__ float bufd[8][128];
    __shared__ int   bufi[8][128];
    int s0 = qg * 8;                        // 8 queries per block, 2 per wave
    const float* xb = x + (size_t)b * (NN * FF);
    const float* xqb = x_sq + (size_t)b * NN;

    // 2 query feature vectors -> SGPRs via readfirstlane (wave-uniform)
    float sa0[32], sa1[32];
    {
        const float* sp0 = sampled + ((size_t)b * SS + s0 + w * 2 + 0) * FF;
        const float* sp1 = sampled + ((size_t)b * SS + s0 + w * 2 + 1) * FF;
#pragma unroll
        for (int k = 0; k < 32; k++) {
            sa0[k] = uni(sp0[k]);
            sa1[k] = uni(sp1[k]);
        }
    }
    float ssq0 = uni(s_sq[b * SS + s0 + w * 2 + 0]);
    float ssq1 = uni(s_sq[b * SS + s0 + w * 2 + 1]);

    float* bq0d = &bufd[w * 2 + 0][0];  int* bq0i = &bufi[w * 2 + 0][0];
    float* bq1d = &bufd[w * 2 + 1][0];  int* bq1i = &bufi[w * 2 + 1][0];
    int   cnt0 = 0, cnt1 = 0;              // wave-uniform (ballot popcounts)
    float tau0 = INFINITY, tau1 = INFINITY;

    // staging geometry: thread stages rows r0 and r0+32, 16B chunk c0
    int r0 = tid >> 3, c0 = (tid & 7) * 4;
    const float4* g0 = (const float4*)(xb + (size_t)r0 * FF + c0);
    const float4* g1 = (const float4*)(xb + (size_t)(r0 + 32) * FF + c0);
    // preamble: tile 0 -> regs; x_sq tile 0 -> reg
    float4 p0 = g0[0], p1 = g1[0];
    float xq = xqb[lane];

    for (int t = 0; t < NN / 64; t++) {
        // write tile t (regs -> LDS), then issue prefetch of tile t+1
        *(float4*)&xs[r0][c0] = p0;
        *(float4*)&xs[r0 + 32][c0] = p1;
        if (t + 1 < NN / 64) {
            p0 = g0[(size_t)(t + 1) * 512];   // 512 float4 = 64 rows
            p1 = g1[(size_t)(t + 1) * 512];
        }
        __syncthreads();                      // tile t writes visible
        int n = t * 64 + lane;
        float xq_c = xq;
        // both dot chains interleaved; ref-exact sequential FMA order each.
        float c0a = 0.f, c1a = 0.f;
        {
            const float4* rr = (const float4*)&xs[lane][0];
#pragma unroll
            for (int j = 0; j < 8; j++) {
                float4 v = rr[j];
                c0a = fmaf(sa0[4 * j], v.x, c0a);     c1a = fmaf(sa1[4 * j], v.x, c1a);
                c0a = fmaf(sa0[4 * j + 1], v.y, c0a); c1a = fmaf(sa1[4 * j + 1], v.y, c1a);
                c0a = fmaf(sa0[4 * j + 2], v.z, c0a); c1a = fmaf(sa1[4 * j + 2], v.z, c1a);
                c0a = fmaf(sa0[4 * j + 3], v.w, c0a); c1a = fmaf(sa1[4 * j + 3], v.w, c1a);
            }
        }
        // prefetch next xq (consumed next iteration)
        if (t + 1 < NN / 64) xq = xqb[(t + 1) * 64 + lane];

        float d0v = (ssq0 + xq_c) - (c0a + c0a);   // ref combine order
        float d1v = (ssq1 + xq_c) - (c1a + c1a);

        unsigned long long m0 = __ballot(d0v < tau0);
        if (m0) {
            int pos = cnt0 + mbcnt64(m0);
            if (d0v < tau0) { bq0d[pos] = d0v; bq0i[pos] = n; }
            cnt0 += __builtin_popcountll(m0);
            if (cnt0 > 64) { tau0 = wave_compact2(bq0d, bq0i, cnt0, lane); cnt0 = 32; }
        }
        unsigned long long m1 = __ballot(d1v < tau1);
        if (m1) {
            int pos = cnt1 + mbcnt64(m1);
            if (d1v < tau1) { bq1d[pos] = d1v; bq1i[pos] = n; }
            cnt1 += __builtin_popcountll(m1);
            if (cnt1 > 64) { tau1 = wave_compact2(bq1d, bq1i, cnt1, lane); cnt1 = 32; }
        }
        __syncthreads();   // tile t reads done; next tile may overwrite xs
    }
    // final: compact (lex-sorts survivors) and emit first 32 per query
    wave_compact2(bq0d, bq0i, cnt0, lane);
    wave_compact2(bq1d, bq1i, cnt1, lane);
    int s = s0 + w * 2;
    if (lane < 32) {
        nbr[((size_t)b * SS + s) * KK + lane] = bq0i[lane];
        nbr[((size_t)b * SS + s + 1) * KK + lane] = bq1i[lane];
    }
}

// ---------------------------------------------------------------------------
// K4: features_batch[b,o,s] = max_k h2[b, nbr[b,s,k], o]; block=128, 16 s/block
__global__ __launch_bounds__(128) void maxgather_kernel(const float* __restrict__ h2,
                                                        const int* __restrict__ nbr,
                                                        float* __restrict__ out_feat) {
    __shared__ float fs[128][17];
    int b = blockIdx.x & 7;
    int sg = blockIdx.x >> 3;               // 0..127
    int s0 = sg * 16;
    int tid = threadIdx.x;                  // o = tid (0..127)
    for (int si = 0; si < 16; si++) {
        int s = s0 + si;
        const int* row = nbr + ((size_t)b * SS + s) * KK;
        float m = -INFINITY;
#pragma unroll 4
        for (int k = 0; k < KK; k++) {
            int idx = row[k];
            float v = h2[((size_t)b * NN + idx) * OUTC + tid];
            m = fmaxf(m, v);
        }
        fs[tid][si] = m;
    }
    __syncthreads();
#pragma unroll
    for (int j = 0; j < 16; j++) {
        int flat = j * 128 + tid;
        int fo = flat >> 4, sw = flat & 15;
        out_feat[((size_t)b * OUTC + fo) * SS + s0 + sw] = fs[fo][sw];
    }
}

// ---------------------------------------------------------------------------
extern "C" void kernel_launch(void* const* d_in, const int* in_sizes, int n_in,
                              void* d_out, int out_size, void* d_ws, size_t ws_size,
                              hipStream_t stream) {
    const float* x    = (const float*)d_in[0];
    const int*   sidx = (const int*)d_in[1];
    const float* W1   = (const float*)d_in[2];
    const float* b1   = (const float*)d_in[3];
    const float* W2   = (const float*)d_in[4];
    const float* b2   = (const float*)d_in[5];

    float* out_feat = (float*)d_out;                       // [B,128,S]
    float* out_samp = out_feat + (size_t)BB * OUTC * SS;   // [B,32,S]

    float* h2      = (float*)d_ws;                         // B*N*128 fp32 = 64 MB
    float* sampled = h2 + (size_t)BB * NN * OUTC;          // B*S*F
    float* xsq     = sampled + (size_t)BB * SS * FF;       // B*N
    float* ssq     = xsq + (size_t)BB * NN;                // B*S
    int*   nbr     = (int*)(ssq + (size_t)BB * SS);        // B*S*K

    xsq_kernel<<<dim3(BB * NN / 256), dim3(256), 0, stream>>>(x, xsq);
    gather_kernel<<<dim3(BB * SS / 256), dim3(256), 0, stream>>>(x, sidx, sampled, ssq);
    mlp_kernel<<<dim3(BB * NN / 64), dim3(256), 0, stream>>>(x, W1, b1, W2, b2, h2);
    transpose_kernel<<<dim3(BB * SS / 64), dim3(256), 0, stream>>>(sampled, out_samp);
    topk_kernel<<<dim3(BB * SS / 8), dim3(256), 0, stream>>>(x, xsq, sampled, ssq, nbr);
    maxgather_kernel<<<dim3(BB * SS / 16), dim3(128), 0, stream>>>(h2, nbr, out_feat);
}

// Round 3
// 1078.452 us; speedup vs baseline: 1.0141x; 1.0092x over previous
//
#include <hip/hip_runtime.h>
#include <math.h>

#pragma clang fp contract(off)   // no implicit fusion; FMA only where ref has it

// Problem constants (fixed by the reference)
#define BB   8
#define NN   16384
#define FF   32
#define SS   2048
#define KK   32
#define OUTC 128

// force a value into uniform (SGPR) representation
__device__ __forceinline__ float uni(float v) {
    return __uint_as_float(__builtin_amdgcn_readfirstlane(__float_as_uint(v)));
}

// prefix popcount of 64-bit ballot below this lane (2 VALU ops)
__device__ __forceinline__ int mbcnt64(unsigned long long m) {
    return __builtin_amdgcn_mbcnt_hi((unsigned)(m >> 32),
           __builtin_amdgcn_mbcnt_lo((unsigned)m, 0));
}

// ---------------------------------------------------------------------------
// Reference-bit-exact fp32 helpers (validated R0-R7):
// x_sq / s_sq: numpy pairwise_sum scalar 8-accumulator block (n=32, no FMA)
__device__ __forceinline__ float np_sumsq32(const float* a) {
    float r[8];
#pragma unroll
    for (int j = 0; j < 8; j++) r[j] = a[j] * a[j];
#pragma unroll
    for (int t = 1; t < 4; t++) {
#pragma unroll
        for (int j = 0; j < 8; j++) {
            float e = a[8 * t + j] * a[8 * t + j];
            r[j] = r[j] + e;
        }
    }
    return ((r[0] + r[1]) + (r[2] + r[3])) + ((r[4] + r[5]) + (r[6] + r[7]));
}

// ---------------------------------------------------------------------------
// K1a: x_sq[b,n] = ref-order sum_f x^2
__global__ __launch_bounds__(256) void xsq_kernel(const float* __restrict__ x,
                                                  float* __restrict__ xsq) {
    int gid = blockIdx.x * 256 + threadIdx.x;      // < B*N
    const float4* r = (const float4*)(x + (size_t)gid * FF);
    float a[32];
#pragma unroll
    for (int j = 0; j < 8; j++) {
        float4 v = r[j];
        a[4 * j] = v.x; a[4 * j + 1] = v.y; a[4 * j + 2] = v.z; a[4 * j + 3] = v.w;
    }
    xsq[gid] = np_sumsq32(a);
}

// ---------------------------------------------------------------------------
// K1b: gather sampled features (row-major [B,S,F]) + ref-order s_sq
__global__ __launch_bounds__(256) void gather_kernel(const float* __restrict__ x,
                                                     const int* __restrict__ sidx,
                                                     float* __restrict__ sampled,
                                                     float* __restrict__ ssq) {
    int gid = blockIdx.x * 256 + threadIdx.x;      // < B*S
    int b = gid >> 11;
    int idx = sidx[gid];
    const float4* r = (const float4*)(x + ((size_t)b * NN + idx) * FF);
    float4* wo = (float4*)(sampled + (size_t)gid * FF);
    float a[32];
#pragma unroll
    for (int j = 0; j < 8; j++) {
        float4 v = r[j];
        a[4 * j] = v.x; a[4 * j + 1] = v.y; a[4 * j + 2] = v.z; a[4 * j + 3] = v.w;
        wo[j] = v;
    }
    ssq[gid] = np_sumsq32(a);
}

// ---------------------------------------------------------------------------
// K1c: sampled [B,S,F] -> output sampled_batch [B,F,S] (transpose via LDS)
__global__ __launch_bounds__(256) void transpose_kernel(const float* __restrict__ sampled,
                                                        float* __restrict__ out_samp) {
    __shared__ float tile[32][65];
    int b = blockIdx.x >> 5, sg = blockIdx.x & 31;
    int s0 = sg * 64;
    int tid = threadIdx.x;
    int f = tid & 31, si = tid >> 5;               // si in 0..7
#pragma unroll
    for (int r = 0; r < 8; r++) {
        int s = r * 8 + si;
        tile[f][s] = sampled[((size_t)b * SS + s0 + s) * FF + f];
    }
    __syncthreads();
#pragma unroll
    for (int r = 0; r < 8; r++) {
        int flat = r * 256 + tid;
        int fo = flat >> 6, sw = flat & 63;
        out_samp[((size_t)b * FF + fo) * SS + s0 + sw] = tile[fo][sw];
    }
}

// ---------------------------------------------------------------------------
// K2: per-point MLP, h2[b,n,:] = W2 @ relu(W1 @ x + b1) + b2  (fp32, VALU)
__global__ __launch_bounds__(256) void mlp_kernel(const float* __restrict__ x,
                                                  const float* __restrict__ W1,
                                                  const float* __restrict__ b1,
                                                  const float* __restrict__ W2,
                                                  const float* __restrict__ b2,
                                                  float* __restrict__ h2) {
    __shared__ float xs[64][36];          // padded
    __shared__ float hs[8512];            // h1t [128][65] then reused as h2s [64][133]
    int tid = threadIdx.x, lane = tid & 63;
    int wu = __builtin_amdgcn_readfirstlane(tid >> 6);
    size_t p0 = (size_t)blockIdx.x * 64;

    for (int i = tid; i < 64 * 8; i += 256) {
        int row = i >> 3, seg = i & 7;
        *(float4*)&xs[row][seg * 4] = *(const float4*)(x + (p0 + row) * FF + seg * 4);
    }
    __syncthreads();

    float xr[32];
    {
        const float4* r = (const float4*)&xs[lane][0];
#pragma unroll
        for (int j = 0; j < 8; j++) {
            float4 v = r[j];
            xr[4 * j] = v.x; xr[4 * j + 1] = v.y; xr[4 * j + 2] = v.z; xr[4 * j + 3] = v.w;
        }
    }
#pragma unroll 4
    for (int i = 0; i < 32; i++) {
        int o = wu * 32 + i;
        const float4* wr = (const float4*)(W1 + o * FF);
        float a = b1[o];
#pragma unroll
        for (int j = 0; j < 8; j++) {
            float4 v = wr[j];
            a = fmaf(v.x, xr[4 * j], a);     a = fmaf(v.y, xr[4 * j + 1], a);
            a = fmaf(v.z, xr[4 * j + 2], a); a = fmaf(v.w, xr[4 * j + 3], a);
        }
        hs[o * 65 + lane] = fmaxf(a, 0.f);
    }
    __syncthreads();
    float acc[32];
#pragma unroll
    for (int i = 0; i < 32; i++) acc[i] = b2[wu * 32 + i];
    for (int k4 = 0; k4 < 32; k4++) {
        float h0 = hs[(4 * k4 + 0) * 65 + lane];
        float h1v = hs[(4 * k4 + 1) * 65 + lane];
        float h2v = hs[(4 * k4 + 2) * 65 + lane];
        float h3v = hs[(4 * k4 + 3) * 65 + lane];
#pragma unroll
        for (int i = 0; i < 32; i++) {
            const float4 v = *(const float4*)(W2 + (wu * 32 + i) * OUTC + 4 * k4);
            acc[i] = fmaf(v.x, h0, acc[i]);  acc[i] = fmaf(v.y, h1v, acc[i]);
            acc[i] = fmaf(v.z, h2v, acc[i]); acc[i] = fmaf(v.w, h3v, acc[i]);
        }
    }
    __syncthreads();
#pragma unroll 4
    for (int i = 0; i < 32; i++) hs[lane * 133 + wu * 32 + i] = acc[i];
    __syncthreads();
    for (int j = 0; j < 32; j++) {
        int flat = j * 256 + tid;
        int p = flat >> 7, o = flat & 127;
        h2[(p0 + p) * OUTC + o] = hs[p * 133 + o];
    }
}

// ---------------------------------------------------------------------------
// K3 v6: single-buffer LDS (17408 B) + register prefetch, as v5, but with
// __launch_bounds__(256, 6) instead of (256, 8).
// R1 post-mortem: (256,8) capped regs at 32 VGPR / 80 SGPR while the kernel
// needs ~40 / ~112 (sa0+sa1 = 64 wave-uniform SGPRs) -> scratch spills:
// WRITE_SIZE 2MB->20MB, FETCH 10.7->21MB; occupancy gain eaten by spill
// traffic, dur unchanged. (256,6) caps at ~85 VGPR / ~133 SGPR: no spills;
// HW occupancy then limited by SGPR file (800/SIMD / 112 = 7 waves/SIMD
// = 28 waves/CU = 87%), LDS allows 9 blocks/CU. Expect the R1-intended
// occupancy win without the spill tax.
// (R2 was a GPUAcquisitionTimeout — this source is an exact resubmit.)
__device__ __forceinline__ bool lessp(float da, int ia, float db, int ib) {
    return da < db || (da == db && ia < ib);
}
__device__ __forceinline__ void cswap(float& d, int& i, int j, bool dirAsc, int lane) {
    float od = __shfl_xor(d, j);
    int   oi = __shfl_xor(i, j);
    bool lower = (lane & j) == 0;
    bool oLess = lessp(od, oi, d, i);
    if (oLess == (lower == dirAsc)) { d = od; i = oi; }
}
__device__ __forceinline__ void sort64(float& d, int& i, bool asc, int lane) {
#pragma unroll
    for (int k = 2; k <= 64; k <<= 1) {
        bool ba = (((lane & k) == 0) == asc);
#pragma unroll
        for (int j = k >> 1; j > 0; j >>= 1) cswap(d, i, j, ba, lane);
    }
}
// sort m valid slots, keep lowest-64 lex-sorted in [0,64); return 32nd-smallest
__device__ __forceinline__ float wave_compact2(float* bd, int* bi, int m, int lane) {
    float d0 = (lane < m) ? bd[lane] : INFINITY;
    int   i0 = (lane < m) ? bi[lane] : 0x7fffffff;
    float d1 = (lane + 64 < m) ? bd[lane + 64] : INFINITY;
    int   i1 = (lane + 64 < m) ? bi[lane + 64] : 0x7fffffff;
    sort64(d0, i0, true, lane);
    sort64(d1, i1, false, lane);
    bool t = lessp(d1, i1, d0, i0);
    float ld = t ? d1 : d0;
    int   li = t ? i1 : i0;
#pragma unroll
    for (int j = 32; j > 0; j >>= 1) cswap(ld, li, j, true, lane);
    bd[lane] = ld; bi[lane] = li;
    return uni(__shfl(ld, 31));            // uniform across wave
}

__global__ __launch_bounds__(256, 6) void topk_kernel(const float* __restrict__ x,
                                                      const float* __restrict__ x_sq,
                                                      const float* __restrict__ sampled,
                                                      const float* __restrict__ s_sq,
                                                      int* __restrict__ nbr) {
    int b = blockIdx.x & 7;                 // XCD-by-batch swizzle
    int qg = blockIdx.x >> 3;               // 0..255
    int tid = threadIdx.x, lane = tid & 63;
    int w = __builtin_amdgcn_readfirstlane(tid >> 6);
    __shared__ float xs[64][36];            // single buffer, padded rows (9216 B)
    __shared__ float bufd[8][128];
    __shared__ int   bufi[8][128];
    int s0 = qg * 8;                        // 8 queries per block, 2 per wave
    const float* xb = x + (size_t)b * (NN * FF);
    const float* xqb = x_sq + (size_t)b * NN;

    // 2 query feature vectors -> SGPRs via readfirstlane (wave-uniform)
    float sa0[32], sa1[32];
    {
        const float* sp0 = sampled + ((size_t)b * SS + s0 + w * 2 + 0) * FF;
        const float* sp1 = sampled + ((size_t)b * SS + s0 + w * 2 + 1) * FF;
#pragma unroll
        for (int k = 0; k < 32; k++) {
            sa0[k] = uni(sp0[k]);
            sa1[k] = uni(sp1[k]);
        }
    }
    float ssq0 = uni(s_sq[b * SS + s0 + w * 2 + 0]);
    float ssq1 = uni(s_sq[b * SS + s0 + w * 2 + 1]);

    float* bq0d = &bufd[w * 2 + 0][0];  int* bq0i = &bufi[w * 2 + 0][0];
    float* bq1d = &bufd[w * 2 + 1][0];  int* bq1i = &bufi[w * 2 + 1][0];
    int   cnt0 = 0, cnt1 = 0;              // wave-uniform (ballot popcounts)
    float tau0 = INFINITY, tau1 = INFINITY;

    // staging geometry: thread stages rows r0 and r0+32, 16B chunk c0
    int r0 = tid >> 3, c0 = (tid & 7) * 4;
    const float4* g0 = (const float4*)(xb + (size_t)r0 * FF + c0);
    const float4* g1 = (const float4*)(xb + (size_t)(r0 + 32) * FF + c0);
    // preamble: tile 0 -> regs; x_sq tile 0 -> reg
    float4 p0 = g0[0], p1 = g1[0];
    float xq = xqb[lane];

    for (int t = 0; t < NN / 64; t++) {
        // write tile t (regs -> LDS), then issue prefetch of tile t+1
        *(float4*)&xs[r0][c0] = p0;
        *(float4*)&xs[r0 + 32][c0] = p1;
        if (t + 1 < NN / 64) {
            p0 = g0[(size_t)(t + 1) * 512];   // 512 float4 = 64 rows
            p1 = g1[(size_t)(t + 1) * 512];
        }
        __syncthreads();                      // tile t writes visible
        int n = t * 64 + lane;
        float xq_c = xq;
        // both dot chains interleaved; ref-exact sequential FMA order each.
        float c0a = 0.f, c1a = 0.f;
        {
            const float4* rr = (const float4*)&xs[lane][0];
#pragma unroll
            for (int j = 0; j < 8; j++) {
                float4 v = rr[j];
                c0a = fmaf(sa0[4 * j], v.x, c0a);     c1a = fmaf(sa1[4 * j], v.x, c1a);
                c0a = fmaf(sa0[4 * j + 1], v.y, c0a); c1a = fmaf(sa1[4 * j + 1], v.y, c1a);
                c0a = fmaf(sa0[4 * j + 2], v.z, c0a); c1a = fmaf(sa1[4 * j + 2], v.z, c1a);
                c0a = fmaf(sa0[4 * j + 3], v.w, c0a); c1a = fmaf(sa1[4 * j + 3], v.w, c1a);
            }
        }
        // prefetch next xq (consumed next iteration)
        if (t + 1 < NN / 64) xq = xqb[(t + 1) * 64 + lane];

        float d0v = (ssq0 + xq_c) - (c0a + c0a);   // ref combine order
        float d1v = (ssq1 + xq_c) - (c1a + c1a);

        unsigned long long m0 = __ballot(d0v < tau0);
        if (m0) {
            int pos = cnt0 + mbcnt64(m0);
            if (d0v < tau0) { bq0d[pos] = d0v; bq0i[pos] = n; }
            cnt0 += __builtin_popcountll(m0);
            if (cnt0 > 64) { tau0 = wave_compact2(bq0d, bq0i, cnt0, lane); cnt0 = 32; }
        }
        unsigned long long m1 = __ballot(d1v < tau1);
        if (m1) {
            int pos = cnt1 + mbcnt64(m1);
            if (d1v < tau1) { bq1d[pos] = d1v; bq1i[pos] = n; }
            cnt1 += __builtin_popcountll(m1);
            if (cnt1 > 64) { tau1 = wave_compact2(bq1d, bq1i, cnt1, lane); cnt1 = 32; }
        }
        __syncthreads();   // tile t reads done; next tile may overwrite xs
    }
    // final: compact (lex-sorts survivors) and emit first 32 per query
    wave_compact2(bq0d, bq0i, cnt0, lane);
    wave_compact2(bq1d, bq1i, cnt1, lane);
    int s = s0 + w * 2;
    if (lane < 32) {
        nbr[((size_t)b * SS + s) * KK + lane] = bq0i[lane];
        nbr[((size_t)b * SS + s + 1) * KK + lane] = bq1i[lane];
    }
}

// ---------------------------------------------------------------------------
// K4: features_batch[b,o,s] = max_k h2[b, nbr[b,s,k], o]; block=128, 16 s/block
__global__ __launch_bounds__(128) void maxgather_kernel(const float* __restrict__ h2,
                                                        const int* __restrict__ nbr,
                                                        float* __restrict__ out_feat) {
    __shared__ float fs[128][17];
    int b = blockIdx.x & 7;
    int sg = blockIdx.x >> 3;               // 0..127
    int s0 = sg * 16;
    int tid = threadIdx.x;                  // o = tid (0..127)
    for (int si = 0; si < 16; si++) {
        int s = s0 + si;
        const int* row = nbr + ((size_t)b * SS + s) * KK;
        float m = -INFINITY;
#pragma unroll 4
        for (int k = 0; k < KK; k++) {
            int idx = row[k];
            float v = h2[((size_t)b * NN + idx) * OUTC + tid];
            m = fmaxf(m, v);
        }
        fs[tid][si] = m;
    }
    __syncthreads();
#pragma unroll
    for (int j = 0; j < 16; j++) {
        int flat = j * 128 + tid;
        int fo = flat >> 4, sw = flat & 15;
        out_feat[((size_t)b * OUTC + fo) * SS + s0 + sw] = fs[fo][sw];
    }
}

// ---------------------------------------------------------------------------
extern "C" void kernel_launch(void* const* d_in, const int* in_sizes, int n_in,
                              void* d_out, int out_size, void* d_ws, size_t ws_size,
                              hipStream_t stream) {
    const float* x    = (const float*)d_in[0];
    const int*   sidx = (const int*)d_in[1];
    const float* W1   = (const float*)d_in[2];
    const float* b1   = (const float*)d_in[3];
    const float* W2   = (const float*)d_in[4];
    const float* b2   = (const float*)d_in[5];

    float* out_feat = (float*)d_out;                       // [B,128,S]
    float* out_samp = out_feat + (size_t)BB * OUTC * SS;   // [B,32,S]

    float* h2      = (float*)d_ws;                         // B*N*128 fp32 = 64 MB
    float* sampled = h2 + (size_t)BB * NN * OUTC;          // B*S*F
    float* xsq     = sampled + (size_t)BB * SS * FF;       // B*N
    float* ssq     = xsq + (size_t)BB * NN;                // B*S
    int*   nbr     = (int*)(ssq + (size_t)BB * SS);        // B*S*K

    xsq_kernel<<<dim3(BB * NN / 256), dim3(256), 0, stream>>>(x, xsq);
    gather_kernel<<<dim3(BB * SS / 256), dim3(256), 0, stream>>>(x, sidx, sampled, ssq);
    mlp_kernel<<<dim3(BB * NN / 64), dim3(256), 0, stream>>>(x, W1, b1, W2, b2, h2);
    transpose_kernel<<<dim3(BB * SS / 64), dim3(256), 0, stream>>>(sampled, out_samp);
    topk_kernel<<<dim3(BB * SS / 8), dim3(256), 0, stream>>>(x, xsq, sampled, ssq, nbr);
    maxgather_kernel<<<dim3(BB * SS / 16), dim3(128), 0, stream>>>(h2, nbr, out_feat);
}

// Round 4
// 1035.172 us; speedup vs baseline: 1.0565x; 1.0418x over previous
//
#include <hip/hip_runtime.h>
#include <math.h>

#pragma clang fp contract(off)   // no implicit fusion; FMA only where ref has it

// Problem constants (fixed by the reference)
#define BB   8
#define NN   16384
#define FF   32
#define SS   2048
#define KK   32
#define OUTC 128

typedef float v2f __attribute__((ext_vector_type(2)));

// force a value into uniform (SGPR) representation
__device__ __forceinline__ float uni(float v) {
    return __uint_as_float(__builtin_amdgcn_readfirstlane(__float_as_uint(v)));
}

__device__ __forceinline__ v2f splat2(float s) { v2f r; r.x = s; r.y = s; return r; }

// prefix popcount of 64-bit ballot below this lane (2 VALU ops)
__device__ __forceinline__ int mbcnt64(unsigned long long m) {
    return __builtin_amdgcn_mbcnt_hi((unsigned)(m >> 32),
           __builtin_amdgcn_mbcnt_lo((unsigned)m, 0));
}

// ---------------------------------------------------------------------------
// Reference-bit-exact fp32 helpers (validated R0-R7):
// x_sq / s_sq: numpy pairwise_sum scalar 8-accumulator block (n=32, no FMA)
__device__ __forceinline__ float np_sumsq32(const float* a) {
    float r[8];
#pragma unroll
    for (int j = 0; j < 8; j++) r[j] = a[j] * a[j];
#pragma unroll
    for (int t = 1; t < 4; t++) {
#pragma unroll
        for (int j = 0; j < 8; j++) {
            float e = a[8 * t + j] * a[8 * t + j];
            r[j] = r[j] + e;
        }
    }
    return ((r[0] + r[1]) + (r[2] + r[3])) + ((r[4] + r[5]) + (r[6] + r[7]));
}

// ---------------------------------------------------------------------------
// K1a: x_sq[b,n] = ref-order sum_f x^2
__global__ __launch_bounds__(256) void xsq_kernel(const float* __restrict__ x,
                                                  float* __restrict__ xsq) {
    int gid = blockIdx.x * 256 + threadIdx.x;      // < B*N
    const float4* r = (const float4*)(x + (size_t)gid * FF);
    float a[32];
#pragma unroll
    for (int j = 0; j < 8; j++) {
        float4 v = r[j];
        a[4 * j] = v.x; a[4 * j + 1] = v.y; a[4 * j + 2] = v.z; a[4 * j + 3] = v.w;
    }
    xsq[gid] = np_sumsq32(a);
}

// ---------------------------------------------------------------------------
// K1b: gather sampled features (row-major [B,S,F]) + ref-order s_sq
__global__ __launch_bounds__(256) void gather_kernel(const float* __restrict__ x,
                                                     const int* __restrict__ sidx,
                                                     float* __restrict__ sampled,
                                                     float* __restrict__ ssq) {
    int gid = blockIdx.x * 256 + threadIdx.x;      // < B*S
    int b = gid >> 11;
    int idx = sidx[gid];
    const float4* r = (const float4*)(x + ((size_t)b * NN + idx) * FF);
    float4* wo = (float4*)(sampled + (size_t)gid * FF);
    float a[32];
#pragma unroll
    for (int j = 0; j < 8; j++) {
        float4 v = r[j];
        a[4 * j] = v.x; a[4 * j + 1] = v.y; a[4 * j + 2] = v.z; a[4 * j + 3] = v.w;
        wo[j] = v;
    }
    ssq[gid] = np_sumsq32(a);
}

// ---------------------------------------------------------------------------
// K1c: sampled [B,S,F] -> output sampled_batch [B,F,S] (transpose via LDS)
__global__ __launch_bounds__(256) void transpose_kernel(const float* __restrict__ sampled,
                                                        float* __restrict__ out_samp) {
    __shared__ float tile[32][65];
    int b = blockIdx.x >> 5, sg = blockIdx.x & 31;
    int s0 = sg * 64;
    int tid = threadIdx.x;
    int f = tid & 31, si = tid >> 5;               // si in 0..7
#pragma unroll
    for (int r = 0; r < 8; r++) {
        int s = r * 8 + si;
        tile[f][s] = sampled[((size_t)b * SS + s0 + s) * FF + f];
    }
    __syncthreads();
#pragma unroll
    for (int r = 0; r < 8; r++) {
        int flat = r * 256 + tid;
        int fo = flat >> 6, sw = flat & 63;
        out_samp[((size_t)b * FF + fo) * SS + s0 + sw] = tile[fo][sw];
    }
}

// ---------------------------------------------------------------------------
// K2: per-point MLP, h2[b,n,:] = W2 @ relu(W1 @ x + b1) + b2  (fp32, VALU)
__global__ __launch_bounds__(256) void mlp_kernel(const float* __restrict__ x,
                                                  const float* __restrict__ W1,
                                                  const float* __restrict__ b1,
                                                  const float* __restrict__ W2,
                                                  const float* __restrict__ b2,
                                                  float* __restrict__ h2) {
    __shared__ float xs[64][36];          // padded
    __shared__ float hs[8512];            // h1t [128][65] then reused as h2s [64][133]
    int tid = threadIdx.x, lane = tid & 63;
    int wu = __builtin_amdgcn_readfirstlane(tid >> 6);
    size_t p0 = (size_t)blockIdx.x * 64;

    for (int i = tid; i < 64 * 8; i += 256) {
        int row = i >> 3, seg = i & 7;
        *(float4*)&xs[row][seg * 4] = *(const float4*)(x + (p0 + row) * FF + seg * 4);
    }
    __syncthreads();

    float xr[32];
    {
        const float4* r = (const float4*)&xs[lane][0];
#pragma unroll
        for (int j = 0; j < 8; j++) {
            float4 v = r[j];
            xr[4 * j] = v.x; xr[4 * j + 1] = v.y; xr[4 * j + 2] = v.z; xr[4 * j + 3] = v.w;
        }
    }
#pragma unroll 4
    for (int i = 0; i < 32; i++) {
        int o = wu * 32 + i;
        const float4* wr = (const float4*)(W1 + o * FF);
        float a = b1[o];
#pragma unroll
        for (int j = 0; j < 8; j++) {
            float4 v = wr[j];
            a = fmaf(v.x, xr[4 * j], a);     a = fmaf(v.y, xr[4 * j + 1], a);
            a = fmaf(v.z, xr[4 * j + 2], a); a = fmaf(v.w, xr[4 * j + 3], a);
        }
        hs[o * 65 + lane] = fmaxf(a, 0.f);
    }
    __syncthreads();
    float acc[32];
#pragma unroll
    for (int i = 0; i < 32; i++) acc[i] = b2[wu * 32 + i];
    for (int k4 = 0; k4 < 32; k4++) {
        float h0 = hs[(4 * k4 + 0) * 65 + lane];
        float h1v = hs[(4 * k4 + 1) * 65 + lane];
        float h2v = hs[(4 * k4 + 2) * 65 + lane];
        float h3v = hs[(4 * k4 + 3) * 65 + lane];
#pragma unroll
        for (int i = 0; i < 32; i++) {
            const float4 v = *(const float4*)(W2 + (wu * 32 + i) * OUTC + 4 * k4);
            acc[i] = fmaf(v.x, h0, acc[i]);  acc[i] = fmaf(v.y, h1v, acc[i]);
            acc[i] = fmaf(v.z, h2v, acc[i]); acc[i] = fmaf(v.w, h3v, acc[i]);
        }
    }
    __syncthreads();
#pragma unroll 4
    for (int i = 0; i < 32; i++) hs[lane * 133 + wu * 32 + i] = acc[i];
    __syncthreads();
    for (int j = 0; j < 32; j++) {
        int flat = j * 256 + tid;
        int p = flat >> 7, o = flat & 127;
        h2[(p0 + p) * OUTC + o] = hs[p * 133 + o];
    }
}

// ---------------------------------------------------------------------------
// K3 v7: packed-FP32 dot chains. R3 post-mortem: spills fixed but occupancy
// pinned at ~48% regardless of LDS/launch-bounds -> occupancy lever dead.
// VALU-issue analysis: FMA floor 109 us, measured VALU-busy ~400 us of an
// 816 us wall. v_pk_fma_f32 (CDNA packed fp32, the source of the 157 TF
// spec) packs query0's chain in .x and query1's in .y: halves FMA issue
// (128->64 cyc/tile/wave) with BIT-IDENTICAL per-chain sequential order.
// Expect dur 816 -> ~620-690, VALUBusy -> ~40-45, absmax unchanged exactly.
__device__ __forceinline__ bool lessp(float da, int ia, float db, int ib) {
    return da < db || (da == db && ia < ib);
}
__device__ __forceinline__ void cswap(float& d, int& i, int j, bool dirAsc, int lane) {
    float od = __shfl_xor(d, j);
    int   oi = __shfl_xor(i, j);
    bool lower = (lane & j) == 0;
    bool oLess = lessp(od, oi, d, i);
    if (oLess == (lower == dirAsc)) { d = od; i = oi; }
}
__device__ __forceinline__ void sort64(float& d, int& i, bool asc, int lane) {
#pragma unroll
    for (int k = 2; k <= 64; k <<= 1) {
        bool ba = (((lane & k) == 0) == asc);
#pragma unroll
        for (int j = k >> 1; j > 0; j >>= 1) cswap(d, i, j, ba, lane);
    }
}
// sort m valid slots, keep lowest-64 lex-sorted in [0,64); return 32nd-smallest
__device__ __forceinline__ float wave_compact2(float* bd, int* bi, int m, int lane) {
    float d0 = (lane < m) ? bd[lane] : INFINITY;
    int   i0 = (lane < m) ? bi[lane] : 0x7fffffff;
    float d1 = (lane + 64 < m) ? bd[lane + 64] : INFINITY;
    int   i1 = (lane + 64 < m) ? bi[lane + 64] : 0x7fffffff;
    sort64(d0, i0, true, lane);
    sort64(d1, i1, false, lane);
    bool t = lessp(d1, i1, d0, i0);
    float ld = t ? d1 : d0;
    int   li = t ? i1 : i0;
#pragma unroll
    for (int j = 32; j > 0; j >>= 1) cswap(ld, li, j, true, lane);
    bd[lane] = ld; bi[lane] = li;
    return uni(__shfl(ld, 31));            // uniform across wave
}

__global__ __launch_bounds__(256, 6) void topk_kernel(const float* __restrict__ x,
                                                      const float* __restrict__ x_sq,
                                                      const float* __restrict__ sampled,
                                                      const float* __restrict__ s_sq,
                                                      int* __restrict__ nbr) {
    int b = blockIdx.x & 7;                 // XCD-by-batch swizzle
    int qg = blockIdx.x >> 3;               // 0..255
    int tid = threadIdx.x, lane = tid & 63;
    int w = __builtin_amdgcn_readfirstlane(tid >> 6);
    __shared__ float xs[64][36];            // single buffer, padded rows (9216 B)
    __shared__ float bufd[8][128];
    __shared__ int   bufi[8][128];
    int s0 = qg * 8;                        // 8 queries per block, 2 per wave
    const float* xb = x + (size_t)b * (NN * FF);
    const float* xqb = x_sq + (size_t)b * NN;

    // 2 query feature vectors, packed {q0,q1} pairs -> wave-uniform (SGPR pairs)
    v2f qp[32];
    {
        const float* sp0 = sampled + ((size_t)b * SS + s0 + w * 2 + 0) * FF;
        const float* sp1 = sampled + ((size_t)b * SS + s0 + w * 2 + 1) * FF;
#pragma unroll
        for (int k = 0; k < 32; k++) {
            qp[k].x = uni(sp0[k]);
            qp[k].y = uni(sp1[k]);
        }
    }
    v2f ssq01;
    ssq01.x = uni(s_sq[b * SS + s0 + w * 2 + 0]);
    ssq01.y = uni(s_sq[b * SS + s0 + w * 2 + 1]);

    float* bq0d = &bufd[w * 2 + 0][0];  int* bq0i = &bufi[w * 2 + 0][0];
    float* bq1d = &bufd[w * 2 + 1][0];  int* bq1i = &bufi[w * 2 + 1][0];
    int   cnt0 = 0, cnt1 = 0;              // wave-uniform (ballot popcounts)
    float tau0 = INFINITY, tau1 = INFINITY;

    // staging geometry: thread stages rows r0 and r0+32, 16B chunk c0
    int r0 = tid >> 3, c0 = (tid & 7) * 4;
    const float4* g0 = (const float4*)(xb + (size_t)r0 * FF + c0);
    const float4* g1 = (const float4*)(xb + (size_t)(r0 + 32) * FF + c0);
    // preamble: tile 0 -> regs; x_sq tile 0 -> reg
    float4 p0 = g0[0], p1 = g1[0];
    float xq = xqb[lane];

    for (int t = 0; t < NN / 64; t++) {
        // write tile t (regs -> LDS), then issue prefetch of tile t+1
        *(float4*)&xs[r0][c0] = p0;
        *(float4*)&xs[r0 + 32][c0] = p1;
        if (t + 1 < NN / 64) {
            p0 = g0[(size_t)(t + 1) * 512];   // 512 float4 = 64 rows
            p1 = g1[(size_t)(t + 1) * 512];
        }
        __syncthreads();                      // tile t writes visible
        int n = t * 64 + lane;
        float xq_c = xq;
        // packed dot chains: .x = query0 chain, .y = query1 chain; each half
        // is the ref-exact sequential FMA order (v_pk_fma_f32 per-half = fmaf)
        v2f c01; c01.x = 0.f; c01.y = 0.f;
        {
            const float4* rr = (const float4*)&xs[lane][0];
#pragma unroll
            for (int j = 0; j < 8; j++) {
                float4 v = rr[j];
                c01 = __builtin_elementwise_fma(qp[4 * j + 0], splat2(v.x), c01);
                c01 = __builtin_elementwise_fma(qp[4 * j + 1], splat2(v.y), c01);
                c01 = __builtin_elementwise_fma(qp[4 * j + 2], splat2(v.z), c01);
                c01 = __builtin_elementwise_fma(qp[4 * j + 3], splat2(v.w), c01);
            }
        }
        // prefetch next xq (consumed next iteration)
        if (t + 1 < NN / 64) xq = xqb[(t + 1) * 64 + lane];

        // ref combine order per half: (ssq + xq) - (c + c)
        v2f d01 = (ssq01 + splat2(xq_c)) - (c01 + c01);
        float d0v = d01.x;
        float d1v = d01.y;

        unsigned long long m0 = __ballot(d0v < tau0);
        if (m0) {
            int pos = cnt0 + mbcnt64(m0);
            if (d0v < tau0) { bq0d[pos] = d0v; bq0i[pos] = n; }
            cnt0 += __builtin_popcountll(m0);
            if (cnt0 > 64) { tau0 = wave_compact2(bq0d, bq0i, cnt0, lane); cnt0 = 32; }
        }
        unsigned long long m1 = __ballot(d1v < tau1);
        if (m1) {
            int pos = cnt1 + mbcnt64(m1);
            if (d1v < tau1) { bq1d[pos] = d1v; bq1i[pos] = n; }
            cnt1 += __builtin_popcountll(m1);
            if (cnt1 > 64) { tau1 = wave_compact2(bq1d, bq1i, cnt1, lane); cnt1 = 32; }
        }
        __syncthreads();   // tile t reads done; next tile may overwrite xs
    }
    // final: compact (lex-sorts survivors) and emit first 32 per query
    wave_compact2(bq0d, bq0i, cnt0, lane);
    wave_compact2(bq1d, bq1i, cnt1, lane);
    int s = s0 + w * 2;
    if (lane < 32) {
        nbr[((size_t)b * SS + s) * KK + lane] = bq0i[lane];
        nbr[((size_t)b * SS + s + 1) * KK + lane] = bq1i[lane];
    }
}

// ---------------------------------------------------------------------------
// K4: features_batch[b,o,s] = max_k h2[b, nbr[b,s,k], o]; block=128, 16 s/block
__global__ __launch_bounds__(128) void maxgather_kernel(const float* __restrict__ h2,
                                                        const int* __restrict__ nbr,
                                                        float* __restrict__ out_feat) {
    __shared__ float fs[128][17];
    int b = blockIdx.x & 7;
    int sg = blockIdx.x >> 3;               // 0..127
    int s0 = sg * 16;
    int tid = threadIdx.x;                  // o = tid (0..127)
    for (int si = 0; si < 16; si++) {
        int s = s0 + si;
        const int* row = nbr + ((size_t)b * SS + s) * KK;
        float m = -INFINITY;
#pragma unroll 4
        for (int k = 0; k < KK; k++) {
            int idx = row[k];
            float v = h2[((size_t)b * NN + idx) * OUTC + tid];
            m = fmaxf(m, v);
        }
        fs[tid][si] = m;
    }
    __syncthreads();
#pragma unroll
    for (int j = 0; j < 16; j++) {
        int flat = j * 128 + tid;
        int fo = flat >> 4, sw = flat & 15;
        out_feat[((size_t)b * OUTC + fo) * SS + s0 + sw] = fs[fo][sw];
    }
}

// ---------------------------------------------------------------------------
extern "C" void kernel_launch(void* const* d_in, const int* in_sizes, int n_in,
                              void* d_out, int out_size, void* d_ws, size_t ws_size,
                              hipStream_t stream) {
    const float* x    = (const float*)d_in[0];
    const int*   sidx = (const int*)d_in[1];
    const float* W1   = (const float*)d_in[2];
    const float* b1   = (const float*)d_in[3];
    const float* W2   = (const float*)d_in[4];
    const float* b2   = (const float*)d_in[5];

    float* out_feat = (float*)d_out;                       // [B,128,S]
    float* out_samp = out_feat + (size_t)BB * OUTC * SS;   // [B,32,S]

    float* h2      = (float*)d_ws;                         // B*N*128 fp32 = 64 MB
    float* sampled = h2 + (size_t)BB * NN * OUTC;          // B*S*F
    float* xsq     = sampled + (size_t)BB * SS * FF;       // B*N
    float* ssq     = xsq + (size_t)BB * NN;                // B*S
    int*   nbr     = (int*)(ssq + (size_t)BB * SS);        // B*S*K

    xsq_kernel<<<dim3(BB * NN / 256), dim3(256), 0, stream>>>(x, xsq);
    gather_kernel<<<dim3(BB * SS / 256), dim3(256), 0, stream>>>(x, sidx, sampled, ssq);
    mlp_kernel<<<dim3(BB * NN / 64), dim3(256), 0, stream>>>(x, W1, b1, W2, b2, h2);
    transpose_kernel<<<dim3(BB * SS / 64), dim3(256), 0, stream>>>(sampled, out_samp);
    topk_kernel<<<dim3(BB * SS / 8), dim3(256), 0, stream>>>(x, xsq, sampled, ssq, nbr);
    maxgather_kernel<<<dim3(BB * SS / 16), dim3(128), 0, stream>>>(h2, nbr, out_feat);
}